// Round 7
// baseline (370.668 us; speedup 1.0000x reference)
//
#include <hip/hip_runtime.h>
#include <hip/hip_bf16.h>

#define NH 8
#define SQ 2048
#define HD 64
#define NTOT (NH * SQ * HD)   // 1048576
#define PIT 72                 // LDS row pitch in u16

typedef unsigned short u16;
typedef unsigned int u32;
typedef __attribute__((ext_vector_type(8))) unsigned short us8;
typedef __attribute__((ext_vector_type(4))) unsigned short us4v;
typedef __attribute__((ext_vector_type(8))) _Float16 h8;   // MFMA f16 A/B fragment
typedef __attribute__((ext_vector_type(4))) float f4;      // MFMA C/D fragment
typedef __attribute__((ext_vector_type(4))) u32 u4;

#define MFMA_F16 __builtin_amdgcn_mfma_f32_16x16x32_f16

__device__ __forceinline__ u16 f2h(float f) {
    union { _Float16 h; u16 u; } c; c.h = (_Float16)f; return c.u;   // v_cvt_f16_f32 RNE
}
__device__ __forceinline__ float h2f(u16 u) {
    union { _Float16 h; u16 u; } c; c.u = u; return (float)c.h;
}
__device__ __forceinline__ h8 neg_h8(h8 a) {
    union { h8 h; u4 u; } c; c.h = a;
    c.u ^= 0x80008000u;
    return c.h;
}
// 8 contiguous f32 -> f16x8 fragment (two float4 loads, hw cvt)
__device__ __forceinline__ h8 pack8h(const float* p) {
    float4 a = ((const float4*)p)[0];
    float4 b = ((const float4*)p)[1];
    h8 r;
    r[0] = (_Float16)a.x; r[1] = (_Float16)a.y; r[2] = (_Float16)a.z; r[3] = (_Float16)a.w;
    r[4] = (_Float16)b.x; r[5] = (_Float16)b.y; r[6] = (_Float16)b.z; r[7] = (_Float16)b.w;
    return r;
}

// ---------------------------------------------------------------------------
// Kernel 1: MFMA complex projections (f32 in -> f16 MFMA -> f16 ws;
// g -> f32 d_out chunks 2,3).  Grid 256 x 256 thr; block = 64 rows,
// wave = 16-row m-tile.  C layout: col = lane&15, row = quad*4 + reg.
// ---------------------------------------------------------------------------
__global__ __launch_bounds__(256) void proj_kernel(
    const float* __restrict__ q_r, const float* __restrict__ q_i,
    const float* __restrict__ k_r, const float* __restrict__ k_i,
    const float* __restrict__ v_r, const float* __restrict__ v_i,
    const float* __restrict__ pe_q_r, const float* __restrict__ pe_q_i,
    const float* __restrict__ pe_k_r, const float* __restrict__ pe_k_i,
    const float* __restrict__ qwr, const float* __restrict__ qwi,
    const float* __restrict__ qbr, const float* __restrict__ qbi,
    const float* __restrict__ kwr, const float* __restrict__ kwi,
    const float* __restrict__ kbr, const float* __restrict__ kbi,
    const float* __restrict__ vwr, const float* __restrict__ vwi,
    const float* __restrict__ vbr, const float* __restrict__ vbi,
    const float* __restrict__ gwr, const float* __restrict__ gwi,
    const float* __restrict__ gbr, const float* __restrict__ gbi,
    u16* __restrict__ q1r, u16* __restrict__ q1i,
    u16* __restrict__ q2r, u16* __restrict__ q2i,
    u16* __restrict__ kpr, u16* __restrict__ kpi,
    u16* __restrict__ vtr, u16* __restrict__ vti,
    float* __restrict__ out_gr, float* __restrict__ out_gi)
{
    const int t = threadIdx.x;
    const int wq = t >> 6, l = t & 63;
    const int quad = l >> 4, m16 = l & 15;
    const int rowbase = blockIdx.x * 64 + wq * 16;   // this wave's m-tile
    const int arow = rowbase + m16;                  // A row this lane loads
    const int h = rowbase >> 11;                     // 32 blocks per head
    const int c0 = quad * 8;                         // within-k-chunk offset

    // ---- loop-invariant A fragments (f32 -> f16) ----
    const float* pqr = q_r + arow * 64;  const float* pqi = q_i + arow * 64;
    const float* pkr = k_r + arow * 64;  const float* pki = k_i + arow * 64;
    const float* pvr = v_r + arow * 64;  const float* pvi = v_i + arow * 64;
    h8 Aqr0 = pack8h(pqr + c0),      Aqr1 = pack8h(pqr + 32 + c0);
    h8 Aqi0 = pack8h(pqi + c0),      Aqi1 = pack8h(pqi + 32 + c0);
    h8 Akr0 = pack8h(pkr + c0),      Akr1 = pack8h(pkr + 32 + c0);
    h8 Aki0 = pack8h(pki + c0),      Aki1 = pack8h(pki + 32 + c0);
    h8 Avr0 = pack8h(pvr + c0),      Avr1 = pack8h(pvr + 32 + c0);
    h8 Avi0 = pack8h(pvi + c0),      Avi1 = pack8h(pvi + 32 + c0);
    h8 nAqi0 = neg_h8(Aqi0),         nAqi1 = neg_h8(Aqi1);
    h8 nAki0 = neg_h8(Aki0),         nAki1 = neg_h8(Aki1);
    h8 nAvi0 = neg_h8(Avi0),         nAvi1 = neg_h8(Avi1);

    // complex 16x16 tile: Cr = Xr Wr^T - Xi Wi^T ; Ci = Xr Wi^T + Xi Wr^T
    auto ctile = [&](h8 Ar0, h8 Ar1, h8 Ai0, h8 Ai1, h8 nAi0, h8 nAi1,
                     const float* wr, const float* wi, int cb,
                     f4& Cr, f4& Ci) {
        const float* wrp = wr + (cb + m16) * 64;
        const float* wip = wi + (cb + m16) * 64;
        h8 Br0 = pack8h(wrp + c0), Br1 = pack8h(wrp + 32 + c0);
        h8 Bi0 = pack8h(wip + c0), Bi1 = pack8h(wip + 32 + c0);
        Cr = (f4)0.f; Ci = (f4)0.f;
        Cr = MFMA_F16(Ar0,  Br0, Cr, 0, 0, 0);
        Cr = MFMA_F16(Ar1,  Br1, Cr, 0, 0, 0);
        Cr = MFMA_F16(nAi0, Bi0, Cr, 0, 0, 0);
        Cr = MFMA_F16(nAi1, Bi1, Cr, 0, 0, 0);
        Ci = MFMA_F16(Ar0,  Bi0, Ci, 0, 0, 0);
        Ci = MFMA_F16(Ar1,  Bi1, Ci, 0, 0, 0);
        Ci = MFMA_F16(Ai0,  Br0, Ci, 0, 0, 0);
        Ci = MFMA_F16(Ai1,  Br1, Ci, 0, 0, 0);
    };

    // ---- q projection: 8 n-tiles, +pe_q (dup'd), deinterleave ----
    for (int nt = 0; nt < 8; ++nt) {
        f4 Cr, Ci;
        ctile(Aqr0, Aqr1, Aqi0, Aqi1, nAqi0, nAqi1, qwr, qwi, nt * 16, Cr, Ci);
        int c = nt * 16 + m16;
        float br = qbr[c], bi = qbi[c];
        int dd = c >> 1;
        int pc = c & 63;
        u16* dR = (c & 1) ? q2r : q1r;
        u16* dI = (c & 1) ? q2i : q1i;
        #pragma unroll
        for (int r = 0; r < 4; ++r) {
            int g = rowbase + quad * 4 + r;
            dR[g * 64 + dd] = f2h(Cr[r] + br + pe_q_r[g * 64 + pc]);
            dI[g * 64 + dd] = f2h(Ci[r] + bi + pe_q_i[g * 64 + pc]);
        }
    }

    // ---- k projection: 4 n-tiles, +pe_k, natural [h][s][d] ----
    for (int nt = 0; nt < 4; ++nt) {
        f4 Cr, Ci;
        ctile(Akr0, Akr1, Aki0, Aki1, nAki0, nAki1, kwr, kwi, nt * 16, Cr, Ci);
        int c = nt * 16 + m16;
        float br = kbr[c], bi = kbi[c];
        #pragma unroll
        for (int r = 0; r < 4; ++r) {
            int g = rowbase + quad * 4 + r;
            kpr[g * 64 + c] = f2h(Cr[r] + br + pe_k_r[g * 64 + c]);
            kpi[g * 64 + c] = f2h(Ci[r] + bi + pe_k_i[g * 64 + c]);
        }
    }

    // ---- v projection: 4 n-tiles, store V^T [h][d][s], 8B packed ----
    for (int nt = 0; nt < 4; ++nt) {
        f4 Cr, Ci;
        ctile(Avr0, Avr1, Avi0, Avi1, nAvi0, nAvi1, vwr, vwi, nt * 16, Cr, Ci);
        int c = nt * 16 + m16;
        float br = vbr[c], bi = vbi[c];
        int s0 = (rowbase & 2047) + quad * 4;
        size_t tix = (size_t)(h * 64 + c) * 2048 + s0;
        us4v pr, pi;
        #pragma unroll
        for (int r = 0; r < 4; ++r) {
            pr[r] = f2h(Cr[r] + br);
            pi[r] = f2h(Ci[r] + bi);
        }
        *(us4v*)&vtr[tix] = pr;
        *(us4v*)&vti[tix] = pi;
    }

    // ---- g projection: 4 n-tiles, f32 to d_out chunks 2,3 ----
    for (int nt = 0; nt < 4; ++nt) {
        f4 Cr, Ci;
        ctile(Aqr0, Aqr1, Aqi0, Aqi1, nAqi0, nAqi1, gwr, gwi, nt * 16, Cr, Ci);
        int c = nt * 16 + m16;
        float br = gbr[c], bi = gbi[c];
        #pragma unroll
        for (int r = 0; r < 4; ++r) {
            int g = rowbase + quad * 4 + r;
            out_gr[g * 64 + c] = Cr[r] + br;
            out_gi[g * 64 + c] = Ci[r] + bi;
        }
    }
}

// ---------------------------------------------------------------------------
// Kernel 2: MFMA flash attention, f16 fragments (structure = round 5/6).
// ---------------------------------------------------------------------------
__global__ __launch_bounds__(256) void attn_kernel(
    const u16* __restrict__ q1r, const u16* __restrict__ q1i,
    const u16* __restrict__ q2r, const u16* __restrict__ q2i,
    const u16* __restrict__ kpr, const u16* __restrict__ kpi,
    const u16* __restrict__ vtr, const u16* __restrict__ vti,
    u16* __restrict__ o1r, u16* __restrict__ o1i,
    u16* __restrict__ o2r, u16* __restrict__ o2i)
{
    __shared__ __align__(16) u16 Kr[64][PIT], Ki[64][PIT];
    __shared__ __align__(16) u16 Vr[64][PIT], Vi[64][PIT];   // V^T tiles: [d][k]
    __shared__ __align__(16) u16 Pb[64][PIT];                // per-wave-private rows

    const int t  = threadIdx.x;
    const int qt = blockIdx.x;   // 0..31
    const int br = blockIdx.y;   // 0..1
    const int h  = blockIdx.z;   // 0..7

    const int wq   = t >> 6;     // wave id -> q rows wq*16..wq*16+15
    const int l    = t & 63;
    const int quad = l >> 4;
    const int m    = l & 15;

    const u16* Qsr = br ? q2r : q1r;
    const u16* Qsi = br ? q2i : q1i;
    const int hbase = h * SQ * 64;
    const int qbase = hbase + qt * 64 * 64;
    const int vbase = h * 64 * SQ;      // [h][d][s]

    const u16* qrr = Qsr + qbase + (wq * 16 + m) * 64;
    const u16* qri = Qsi + qbase + (wq * 16 + m) * 64;
    h8 Qr0 = *(const h8*)(qrr + quad * 8);
    h8 Qr1 = *(const h8*)(qrr + 32 + quad * 8);
    h8 Qi0 = *(const h8*)(qri + quad * 8);
    h8 Qi1 = *(const h8*)(qri + 32 + quad * 8);
    h8 nQr0 = neg_h8(Qr0);
    h8 nQr1 = neg_h8(Qr1);

    float mreg[4], lreg[4];
    #pragma unroll
    for (int r = 0; r < 4; ++r) { mreg[r] = -1e30f; lreg[r] = 0.f; }
    f4 Ovr[4], Ovi[4];
    #pragma unroll
    for (int d = 0; d < 4; ++d) { Ovr[d] = (f4)0.f; Ovi[d] = (f4)0.f; }

    for (int kt = 0; kt < 32; ++kt) {
        __syncthreads();
        {
            const int kb = hbase + kt * 64 * 64;   // K tile (natural)
            const int vb = vbase + kt * 64;        // V^T tile ([d][s])
            for (int i = t; i < 512; i += 256) {
                int r = i >> 3, c8 = (i & 7) * 8;
                *(us8*)&Kr[r][c8] = *(const us8*)(kpr + kb + r * 64 + c8);
                *(us8*)&Ki[r][c8] = *(const us8*)(kpi + kb + r * 64 + c8);
                *(us8*)&Vr[r][c8] = *(const us8*)(vtr + vb + r * SQ + c8);
                *(us8*)&Vi[r][c8] = *(const us8*)(vti + vb + r * SQ + c8);
            }
        }
        __syncthreads();

        float sv[4][4];
        #pragma unroll
        for (int nt = 0; nt < 4; ++nt) {
            const int kr = nt * 16 + m;
            h8 k0 = *(const h8*)&Kr[kr][quad * 8];
            h8 k1 = *(const h8*)&Kr[kr][32 + quad * 8];
            h8 c0 = *(const h8*)&Ki[kr][quad * 8];
            h8 c1 = *(const h8*)&Ki[kr][32 + quad * 8];
            f4 ar = (f4)0.f, ai = (f4)0.f;
            ar = MFMA_F16(Qr0, k0, ar, 0, 0, 0);
            ar = MFMA_F16(Qr1, k1, ar, 0, 0, 0);
            ar = MFMA_F16(Qi0, c0, ar, 0, 0, 0);
            ar = MFMA_F16(Qi1, c1, ar, 0, 0, 0);
            ai = MFMA_F16(Qi0, k0, ai, 0, 0, 0);
            ai = MFMA_F16(Qi1, k1, ai, 0, 0, 0);
            ai = MFMA_F16(nQr0, c0, ai, 0, 0, 0);
            ai = MFMA_F16(nQr1, c1, ai, 0, 0, 0);
            #pragma unroll
            for (int r = 0; r < 4; ++r)
                sv[nt][r] = sqrtf(ar[r] * ar[r] + ai[r] * ai[r] + 1e-8f) * 0.125f;
        }

        float al[4];
        #pragma unroll
        for (int r = 0; r < 4; ++r) {
            float rv = fmaxf(fmaxf(sv[0][r], sv[1][r]), fmaxf(sv[2][r], sv[3][r]));
            rv = fmaxf(rv, __shfl_xor(rv, 1));
            rv = fmaxf(rv, __shfl_xor(rv, 2));
            rv = fmaxf(rv, __shfl_xor(rv, 4));
            rv = fmaxf(rv, __shfl_xor(rv, 8));
            float mn = fmaxf(mreg[r], rv);
            al[r] = __expf(mreg[r] - mn);
            mreg[r] = mn;
            float ls = 0.f;
            #pragma unroll
            for (int nt = 0; nt < 4; ++nt) {
                u16 pb = f2h(__expf(sv[nt][r] - mn));
                Pb[wq * 16 + quad * 4 + r][nt * 16 + m] = pb;
                ls += h2f(pb);
            }
            ls += __shfl_xor(ls, 1);
            ls += __shfl_xor(ls, 2);
            ls += __shfl_xor(ls, 4);
            ls += __shfl_xor(ls, 8);
            lreg[r] = lreg[r] * al[r] + ls;
        }
        // Pb rows are per-wave private: same-wave write->read, compiler
        // inserts the lgkmcnt wait; no __syncthreads needed.

        h8 pa0 = *(const h8*)&Pb[wq * 16 + m][quad * 8];
        h8 pa1 = *(const h8*)&Pb[wq * 16 + m][32 + quad * 8];
        #pragma unroll
        for (int dt = 0; dt < 4; ++dt) {
            #pragma unroll
            for (int r = 0; r < 4; ++r) { Ovr[dt][r] *= al[r]; Ovi[dt][r] *= al[r]; }
            const int vr_ = dt * 16 + m;
            h8 b0 = *(const h8*)&Vr[vr_][quad * 8];
            h8 b1 = *(const h8*)&Vr[vr_][32 + quad * 8];
            h8 d0 = *(const h8*)&Vi[vr_][quad * 8];
            h8 d1 = *(const h8*)&Vi[vr_][32 + quad * 8];
            Ovr[dt] = MFMA_F16(pa0, b0, Ovr[dt], 0, 0, 0);
            Ovr[dt] = MFMA_F16(pa1, b1, Ovr[dt], 0, 0, 0);
            Ovi[dt] = MFMA_F16(pa0, d0, Ovi[dt], 0, 0, 0);
            Ovi[dt] = MFMA_F16(pa1, d1, Ovi[dt], 0, 0, 0);
        }
    }

    {
        u16* Dr = br ? o2r : o1r;
        u16* Di = br ? o2i : o1i;
        float inv[4];
        #pragma unroll
        for (int r = 0; r < 4; ++r) inv[r] = 1.f / lreg[r];
        #pragma unroll
        for (int dt = 0; dt < 4; ++dt) {
            #pragma unroll
            for (int r = 0; r < 4; ++r) {
                int q = wq * 16 + quad * 4 + r;
                Dr[qbase + q * 64 + dt * 16 + m] = f2h(Ovr[dt][r] * inv[r]);
                Di[qbase + q * 64 + dt * 16 + m] = f2h(Ovi[dt][r] * inv[r]);
            }
        }
    }
}

// ---------------------------------------------------------------------------
// Kernel 3: epilogue (f32 math, f16 ws reads — structure unchanged).
// ---------------------------------------------------------------------------
__global__ __launch_bounds__(256) void epi_kernel(
    const u16* __restrict__ o1r, const u16* __restrict__ o1i,
    const u16* __restrict__ o2r, const u16* __restrict__ o2i,
    const float* __restrict__ out_gr, const float* __restrict__ out_gi,
    const float* __restrict__ subw,
    const float* __restrict__ owr, const float* __restrict__ owi,
    const float* __restrict__ obr, const float* __restrict__ obi,
    float* __restrict__ out_r, float* __restrict__ out_i)
{
    __shared__ float xr_s[4][64], xi_s[4][64];

    const int t = threadIdx.x, ty = t >> 6, lane = t & 63;
    const int row = blockIdx.x * 4 + ty;
    const int base = row * 64;

    float a1r = h2f(o1r[base + lane]), a1i = h2f(o1i[base + lane]);
    float a2r = h2f(o2r[base + lane]), a2i = h2f(o2i[base + lane]);

    float ss = a1r * a1r + a1i * a1i + a2r * a2r + a2i * a2i;
    #pragma unroll
    for (int m = 1; m < 64; m <<= 1) ss += __shfl_xor(ss, m);
    float inv = 1.f / sqrtf(ss * (1.f / 128.f) + 1e-5f);

    int src = lane >> 1;
    float e1r = __shfl(a1r, src), e1i = __shfl(a1i, src);
    float e2r = __shfl(a2r, src), e2i = __shfl(a2i, src);
    float c_r = (lane & 1) ? e2r : e1r;
    float c_i = (lane & 1) ? e2i : e1i;

    float sw = subw[lane];
    float ar_ = c_r * inv * sw;
    float ai_ = c_i * inv * sw;

    float g_r = out_gr[base + lane], g_i = out_gi[base + lane];
    xr_s[ty][lane] = g_r * ar_ - g_i * ai_;
    xi_s[ty][lane] = g_r * ai_ + g_i * ar_;
    __syncthreads();

    float accr = 0.f, acci = 0.f;
    const float4* wr4 = (const float4*)(owr + lane * 64);
    const float4* wi4 = (const float4*)(owi + lane * 64);
    #pragma unroll 4
    for (int d4 = 0; d4 < 16; ++d4) {
        float4 a = wr4[d4];
        float4 b = wi4[d4];
        const float* av = (const float*)&a;
        const float* bv = (const float*)&b;
        #pragma unroll
        for (int j = 0; j < 4; ++j) {
            float xrv = xr_s[ty][d4 * 4 + j], xiv = xi_s[ty][d4 * 4 + j];
            accr += xrv * av[j] - xiv * bv[j];
            acci += xrv * bv[j] + xiv * av[j];
        }
    }
    out_r[base + lane] = accr + obr[lane];
    out_i[base + lane] = acci + obi[lane];
}

// ---------------------------------------------------------------------------
extern "C" void kernel_launch(void* const* d_in, const int* in_sizes, int n_in,
                              void* d_out, int out_size, void* d_ws, size_t ws_size,
                              hipStream_t stream)
{
    (void)in_sizes; (void)n_in; (void)out_size; (void)ws_size;

    float* out    = (float*)d_out;
    float* out_r  = out;
    float* out_i  = out + (size_t)NTOT;
    float* out_gr = out + 2 * (size_t)NTOT;
    float* out_gi = out + 3 * (size_t)NTOT;

    // workspace layout (f16 only), 24 MB total
    char* w = (char*)d_ws;
    const size_t N = (size_t)NTOT;
    u16* q1r = (u16*)w; w += N * 2;
    u16* q1i = (u16*)w; w += N * 2;
    u16* q2r = (u16*)w; w += N * 2;
    u16* q2i = (u16*)w; w += N * 2;
    u16* kpr = (u16*)w; w += N * 2;
    u16* kpi = (u16*)w; w += N * 2;
    u16* vtr = (u16*)w; w += N * 2;   // [h][d][s]
    u16* vti = (u16*)w; w += N * 2;   // [h][d][s]
    u16* o1r = (u16*)w; w += N * 2;
    u16* o1i = (u16*)w; w += N * 2;
    u16* o2r = (u16*)w; w += N * 2;
    u16* o2i = (u16*)w; w += N * 2;

    proj_kernel<<<dim3(256), dim3(256), 0, stream>>>(
        (const float*)d_in[0], (const float*)d_in[1],
        (const float*)d_in[2], (const float*)d_in[3],
        (const float*)d_in[4], (const float*)d_in[5],
        (const float*)d_in[6], (const float*)d_in[7],
        (const float*)d_in[8], (const float*)d_in[9],
        (const float*)d_in[10], (const float*)d_in[11],
        (const float*)d_in[12], (const float*)d_in[13],
        (const float*)d_in[14], (const float*)d_in[15],
        (const float*)d_in[16], (const float*)d_in[17],
        (const float*)d_in[18], (const float*)d_in[19],
        (const float*)d_in[20], (const float*)d_in[21],
        (const float*)d_in[22], (const float*)d_in[23],
        (const float*)d_in[24], (const float*)d_in[25],
        q1r, q1i, q2r, q2i, kpr, kpi, vtr, vti, out_gr, out_gi);

    attn_kernel<<<dim3(SQ / 64, 2, NH), dim3(256), 0, stream>>>(
        q1r, q1i, q2r, q2i, kpr, kpi, vtr, vti, o1r, o1i, o2r, o2i);

    epi_kernel<<<dim3(NH * SQ / 4), dim3(256), 0, stream>>>(
        o1r, o1i, o2r, o2i, out_gr, out_gi,
        (const float*)d_in[34], (const float*)d_in[26], (const float*)d_in[27],
        (const float*)d_in[28], (const float*)d_in[29],
        out_r, out_i);
}

// Round 8
// 360.634 us; speedup vs baseline: 1.0278x; 1.0278x over previous
//
#include <hip/hip_runtime.h>
#include <hip/hip_bf16.h>

#define NH 8
#define SQ 2048
#define HD 64
#define NTOT (NH * SQ * HD)   // 1048576
#define PIT 72                 // LDS row pitch in u16

typedef unsigned short u16;
typedef unsigned int u32;
typedef __attribute__((ext_vector_type(8))) unsigned short us8;
typedef __attribute__((ext_vector_type(4))) unsigned short us4v;
typedef __attribute__((ext_vector_type(8))) _Float16 h8;   // MFMA f16 A/B fragment
typedef __attribute__((ext_vector_type(4))) float f4;      // MFMA C/D fragment
typedef __attribute__((ext_vector_type(4))) u32 u4;

#define MFMA_F16 __builtin_amdgcn_mfma_f32_16x16x32_f16

__device__ __forceinline__ u16 f2h(float f) {
    union { _Float16 h; u16 u; } c; c.h = (_Float16)f; return c.u;
}
__device__ __forceinline__ float h2f(u16 u) {
    union { _Float16 h; u16 u; } c; c.u = u; return (float)c.h;
}
__device__ __forceinline__ h8 neg_h8(h8 a) {
    union { h8 h; u4 u; } c; c.h = a;
    c.u ^= 0x80008000u;
    return c.h;
}
// 8 contiguous f32 -> f16x8 fragment (two float4 loads, hw cvt)
__device__ __forceinline__ h8 pack8h(const float* p) {
    float4 a = ((const float4*)p)[0];
    float4 b = ((const float4*)p)[1];
    h8 r;
    r[0] = (_Float16)a.x; r[1] = (_Float16)a.y; r[2] = (_Float16)a.z; r[3] = (_Float16)a.w;
    r[4] = (_Float16)b.x; r[5] = (_Float16)b.y; r[6] = (_Float16)b.z; r[7] = (_Float16)b.w;
    return r;
}

struct Afrag { h8 r0, r1, i0, i1, ni0, ni1; };

// ---------------------------------------------------------------------------
// Kernel 1: MFMA complex projections, n-split across waves for occupancy.
// Grid 1024 x 256 thr; block = 16 rows; each wave owns 5 of 20 n-tiles:
//   w0: q0-4 | w1: q5-7, g0-1 | w2: k0-3, g2 | w3: v0-3, g3
// (g uses the same A fragments as q: raw q input.)
// C layout: col = lane&15, row = quad*4 + reg.
// ---------------------------------------------------------------------------
__global__ __launch_bounds__(256) void proj_kernel(
    const float* __restrict__ q_r, const float* __restrict__ q_i,
    const float* __restrict__ k_r, const float* __restrict__ k_i,
    const float* __restrict__ v_r, const float* __restrict__ v_i,
    const float* __restrict__ pe_q_r, const float* __restrict__ pe_q_i,
    const float* __restrict__ pe_k_r, const float* __restrict__ pe_k_i,
    const float* __restrict__ qwr, const float* __restrict__ qwi,
    const float* __restrict__ qbr, const float* __restrict__ qbi,
    const float* __restrict__ kwr, const float* __restrict__ kwi,
    const float* __restrict__ kbr, const float* __restrict__ kbi,
    const float* __restrict__ vwr, const float* __restrict__ vwi,
    const float* __restrict__ vbr, const float* __restrict__ vbi,
    const float* __restrict__ gwr, const float* __restrict__ gwi,
    const float* __restrict__ gbr, const float* __restrict__ gbi,
    u16* __restrict__ q1r, u16* __restrict__ q1i,
    u16* __restrict__ q2r, u16* __restrict__ q2i,
    u16* __restrict__ kpr, u16* __restrict__ kpi,
    u16* __restrict__ vtr, u16* __restrict__ vti,
    float* __restrict__ out_gr, float* __restrict__ out_gi)
{
    const int t = threadIdx.x;
    const int wv = t >> 6, l = t & 63;
    const int quad = l >> 4, m16 = l & 15;
    const int rowbase = blockIdx.x * 16;             // block = one 16-row m-tile
    const int arow = rowbase + m16;                  // A row this lane loads
    const int h = rowbase >> 11;                     // 128 blocks per head
    const int c0 = quad * 8;                         // within-k-chunk offset

    auto loadA = [&](const float* pr, const float* pi) {
        Afrag a;
        const float* rp = pr + arow * 64;
        const float* ip = pi + arow * 64;
        a.r0 = pack8h(rp + c0);      a.r1 = pack8h(rp + 32 + c0);
        a.i0 = pack8h(ip + c0);      a.i1 = pack8h(ip + 32 + c0);
        a.ni0 = neg_h8(a.i0);        a.ni1 = neg_h8(a.i1);
        return a;
    };

    // complex 16x16 tile: Cr = Xr Wr^T - Xi Wi^T ; Ci = Xr Wi^T + Xi Wr^T
    auto ctile = [&](const Afrag& A, const float* wr, const float* wi, int cb,
                     f4& Cr, f4& Ci) {
        const float* wrp = wr + (cb + m16) * 64;
        const float* wip = wi + (cb + m16) * 64;
        h8 Br0 = pack8h(wrp + c0), Br1 = pack8h(wrp + 32 + c0);
        h8 Bi0 = pack8h(wip + c0), Bi1 = pack8h(wip + 32 + c0);
        Cr = (f4)0.f; Ci = (f4)0.f;
        Cr = MFMA_F16(A.r0,  Br0, Cr, 0, 0, 0);
        Cr = MFMA_F16(A.r1,  Br1, Cr, 0, 0, 0);
        Cr = MFMA_F16(A.ni0, Bi0, Cr, 0, 0, 0);
        Cr = MFMA_F16(A.ni1, Bi1, Cr, 0, 0, 0);
        Ci = MFMA_F16(A.r0,  Bi0, Ci, 0, 0, 0);
        Ci = MFMA_F16(A.r1,  Bi1, Ci, 0, 0, 0);
        Ci = MFMA_F16(A.i0,  Br0, Ci, 0, 0, 0);
        Ci = MFMA_F16(A.i1,  Br1, Ci, 0, 0, 0);
    };

    auto qtile = [&](const Afrag& A, int nt) {
        f4 Cr, Ci;
        ctile(A, qwr, qwi, nt * 16, Cr, Ci);
        int c = nt * 16 + m16;
        float br = qbr[c], bi = qbi[c];
        int dd = c >> 1, pc = c & 63;
        u16* dR = (c & 1) ? q2r : q1r;
        u16* dI = (c & 1) ? q2i : q1i;
        #pragma unroll
        for (int r = 0; r < 4; ++r) {
            int g = rowbase + quad * 4 + r;
            dR[g * 64 + dd] = f2h(Cr[r] + br + pe_q_r[g * 64 + pc]);
            dI[g * 64 + dd] = f2h(Ci[r] + bi + pe_q_i[g * 64 + pc]);
        }
    };
    auto ktile = [&](const Afrag& A, int nt) {
        f4 Cr, Ci;
        ctile(A, kwr, kwi, nt * 16, Cr, Ci);
        int c = nt * 16 + m16;
        float br = kbr[c], bi = kbi[c];
        #pragma unroll
        for (int r = 0; r < 4; ++r) {
            int g = rowbase + quad * 4 + r;
            kpr[g * 64 + c] = f2h(Cr[r] + br + pe_k_r[g * 64 + c]);
            kpi[g * 64 + c] = f2h(Ci[r] + bi + pe_k_i[g * 64 + c]);
        }
    };
    auto vtile = [&](const Afrag& A, int nt) {
        f4 Cr, Ci;
        ctile(A, vwr, vwi, nt * 16, Cr, Ci);
        int c = nt * 16 + m16;
        float br = vbr[c], bi = vbi[c];
        int s0 = (rowbase & 2047) + quad * 4;
        size_t tix = (size_t)(h * 64 + c) * 2048 + s0;
        us4v pr, pi;
        #pragma unroll
        for (int r = 0; r < 4; ++r) {
            pr[r] = f2h(Cr[r] + br);
            pi[r] = f2h(Ci[r] + bi);
        }
        *(us4v*)&vtr[tix] = pr;
        *(us4v*)&vti[tix] = pi;
    };
    auto gtile = [&](const Afrag& A, int nt) {
        f4 Cr, Ci;
        ctile(A, gwr, gwi, nt * 16, Cr, Ci);
        int c = nt * 16 + m16;
        float br = gbr[c], bi = gbi[c];
        #pragma unroll
        for (int r = 0; r < 4; ++r) {
            int g = rowbase + quad * 4 + r;
            out_gr[g * 64 + c] = Cr[r] + br;
            out_gi[g * 64 + c] = Ci[r] + bi;
        }
    };

    if (wv == 0) {
        Afrag Aq = loadA(q_r, q_i);
        qtile(Aq, 0); qtile(Aq, 1); qtile(Aq, 2); qtile(Aq, 3); qtile(Aq, 4);
    } else if (wv == 1) {
        Afrag Aq = loadA(q_r, q_i);
        qtile(Aq, 5); qtile(Aq, 6); qtile(Aq, 7);
        gtile(Aq, 0); gtile(Aq, 1);
    } else if (wv == 2) {
        Afrag Ak = loadA(k_r, k_i);
        ktile(Ak, 0); ktile(Ak, 1); ktile(Ak, 2); ktile(Ak, 3);
        Afrag Aq = loadA(q_r, q_i);
        gtile(Aq, 2);
    } else {
        Afrag Av = loadA(v_r, v_i);
        vtile(Av, 0); vtile(Av, 1); vtile(Av, 2); vtile(Av, 3);
        Afrag Aq = loadA(q_r, q_i);
        gtile(Aq, 3);
    }
}

// ---------------------------------------------------------------------------
// Kernel 2: MFMA flash attention, f16 fragments.  l via MFMA-ones.
// ---------------------------------------------------------------------------
__global__ __launch_bounds__(256) void attn_kernel(
    const u16* __restrict__ q1r, const u16* __restrict__ q1i,
    const u16* __restrict__ q2r, const u16* __restrict__ q2i,
    const u16* __restrict__ kpr, const u16* __restrict__ kpi,
    const u16* __restrict__ vtr, const u16* __restrict__ vti,
    u16* __restrict__ o1r, u16* __restrict__ o1i,
    u16* __restrict__ o2r, u16* __restrict__ o2i)
{
    __shared__ __align__(16) u16 Kr[64][PIT], Ki[64][PIT];
    __shared__ __align__(16) u16 Vr[64][PIT], Vi[64][PIT];   // V^T tiles: [d][k]
    __shared__ __align__(16) u16 Pb[64][PIT];                // per-wave-private rows

    const int t  = threadIdx.x;
    const int qt = blockIdx.x;   // 0..31
    const int br = blockIdx.y;   // 0..1
    const int h  = blockIdx.z;   // 0..7

    const int wq   = t >> 6;     // wave id -> q rows wq*16..wq*16+15
    const int l    = t & 63;
    const int quad = l >> 4;
    const int m    = l & 15;

    const u16* Qsr = br ? q2r : q1r;
    const u16* Qsi = br ? q2i : q1i;
    const int hbase = h * SQ * 64;
    const int qbase = hbase + qt * 64 * 64;
    const int vbase = h * 64 * SQ;      // [h][d][s]

    const u16* qrr = Qsr + qbase + (wq * 16 + m) * 64;
    const u16* qri = Qsi + qbase + (wq * 16 + m) * 64;
    h8 Qr0 = *(const h8*)(qrr + quad * 8);
    h8 Qr1 = *(const h8*)(qrr + 32 + quad * 8);
    h8 Qi0 = *(const h8*)(qri + quad * 8);
    h8 Qi1 = *(const h8*)(qri + 32 + quad * 8);
    h8 nQr0 = neg_h8(Qr0);
    h8 nQr1 = neg_h8(Qr1);

    h8 ones;
    #pragma unroll
    for (int j = 0; j < 8; ++j) ones[j] = (_Float16)1.0f;

    float mreg[4];
    #pragma unroll
    for (int r = 0; r < 4; ++r) mreg[r] = -1e30f;
    f4 Ovr[4], Ovi[4], Lacc = (f4)0.f;
    #pragma unroll
    for (int d = 0; d < 4; ++d) { Ovr[d] = (f4)0.f; Ovi[d] = (f4)0.f; }

    for (int kt = 0; kt < 32; ++kt) {
        __syncthreads();
        {
            const int kb = hbase + kt * 64 * 64;   // K tile (natural)
            const int vb = vbase + kt * 64;        // V^T tile ([d][s])
            for (int i = t; i < 512; i += 256) {
                int r = i >> 3, c8 = (i & 7) * 8;
                *(us8*)&Kr[r][c8] = *(const us8*)(kpr + kb + r * 64 + c8);
                *(us8*)&Ki[r][c8] = *(const us8*)(kpi + kb + r * 64 + c8);
                *(us8*)&Vr[r][c8] = *(const us8*)(vtr + vb + r * SQ + c8);
                *(us8*)&Vi[r][c8] = *(const us8*)(vti + vb + r * SQ + c8);
            }
        }
        __syncthreads();

        float sv[4][4];
        #pragma unroll
        for (int nt = 0; nt < 4; ++nt) {
            const int kr = nt * 16 + m;
            h8 k0 = *(const h8*)&Kr[kr][quad * 8];
            h8 k1 = *(const h8*)&Kr[kr][32 + quad * 8];
            h8 c0 = *(const h8*)&Ki[kr][quad * 8];
            h8 c1 = *(const h8*)&Ki[kr][32 + quad * 8];
            f4 ar = (f4)0.f, ai = (f4)0.f;
            ar = MFMA_F16(Qr0, k0, ar, 0, 0, 0);
            ar = MFMA_F16(Qr1, k1, ar, 0, 0, 0);
            ar = MFMA_F16(Qi0, c0, ar, 0, 0, 0);
            ar = MFMA_F16(Qi1, c1, ar, 0, 0, 0);
            ai = MFMA_F16(Qi0, k0, ai, 0, 0, 0);
            ai = MFMA_F16(Qi1, k1, ai, 0, 0, 0);
            ai = MFMA_F16(nQr0, c0, ai, 0, 0, 0);
            ai = MFMA_F16(nQr1, c1, ai, 0, 0, 0);
            #pragma unroll
            for (int r = 0; r < 4; ++r)
                sv[nt][r] = sqrtf(ar[r] * ar[r] + ai[r] * ai[r] + 1e-8f) * 0.125f;
        }

        // online-softmax max + P write (l comes from MFMA below)
        float al[4];
        #pragma unroll
        for (int r = 0; r < 4; ++r) {
            float rv = fmaxf(fmaxf(sv[0][r], sv[1][r]), fmaxf(sv[2][r], sv[3][r]));
            rv = fmaxf(rv, __shfl_xor(rv, 1));
            rv = fmaxf(rv, __shfl_xor(rv, 2));
            rv = fmaxf(rv, __shfl_xor(rv, 4));
            rv = fmaxf(rv, __shfl_xor(rv, 8));
            float mn = fmaxf(mreg[r], rv);
            al[r] = __expf(mreg[r] - mn);
            mreg[r] = mn;
            #pragma unroll
            for (int nt = 0; nt < 4; ++nt)
                Pb[wq * 16 + quad * 4 + r][nt * 16 + m] = f2h(__expf(sv[nt][r] - mn));
        }
        // Pb rows are per-wave private: same-wave write->read, compiler
        // inserts the lgkmcnt wait; no __syncthreads needed.

        h8 pa0 = *(const h8*)&Pb[wq * 16 + m][quad * 8];
        h8 pa1 = *(const h8*)&Pb[wq * 16 + m][32 + quad * 8];

        // l row-sum via MFMA with ones-B (sums the rounded f16 P exactly)
        #pragma unroll
        for (int r = 0; r < 4; ++r) Lacc[r] *= al[r];
        Lacc = MFMA_F16(pa0, ones, Lacc, 0, 0, 0);
        Lacc = MFMA_F16(pa1, ones, Lacc, 0, 0, 0);

        #pragma unroll
        for (int dt = 0; dt < 4; ++dt) {
            #pragma unroll
            for (int r = 0; r < 4; ++r) { Ovr[dt][r] *= al[r]; Ovi[dt][r] *= al[r]; }
            const int vr_ = dt * 16 + m;
            h8 b0 = *(const h8*)&Vr[vr_][quad * 8];
            h8 b1 = *(const h8*)&Vr[vr_][32 + quad * 8];
            h8 d0 = *(const h8*)&Vi[vr_][quad * 8];
            h8 d1 = *(const h8*)&Vi[vr_][32 + quad * 8];
            Ovr[dt] = MFMA_F16(pa0, b0, Ovr[dt], 0, 0, 0);
            Ovr[dt] = MFMA_F16(pa1, b1, Ovr[dt], 0, 0, 0);
            Ovi[dt] = MFMA_F16(pa0, d0, Ovi[dt], 0, 0, 0);
            Ovi[dt] = MFMA_F16(pa1, d1, Ovi[dt], 0, 0, 0);
        }
    }

    {
        u16* Dr = br ? o2r : o1r;
        u16* Di = br ? o2i : o1i;
        float inv[4];
        #pragma unroll
        for (int r = 0; r < 4; ++r) inv[r] = 1.f / Lacc[r];
        #pragma unroll
        for (int dt = 0; dt < 4; ++dt) {
            #pragma unroll
            for (int r = 0; r < 4; ++r) {
                int q = wq * 16 + quad * 4 + r;
                Dr[qbase + q * 64 + dt * 16 + m] = f2h(Ovr[dt][r] * inv[r]);
                Di[qbase + q * 64 + dt * 16 + m] = f2h(Ovi[dt][r] * inv[r]);
            }
        }
    }
}

// ---------------------------------------------------------------------------
// Kernel 3: epilogue (f32 math, f16 ws reads — structure unchanged).
// ---------------------------------------------------------------------------
__global__ __launch_bounds__(256) void epi_kernel(
    const u16* __restrict__ o1r, const u16* __restrict__ o1i,
    const u16* __restrict__ o2r, const u16* __restrict__ o2i,
    const float* __restrict__ out_gr, const float* __restrict__ out_gi,
    const float* __restrict__ subw,
    const float* __restrict__ owr, const float* __restrict__ owi,
    const float* __restrict__ obr, const float* __restrict__ obi,
    float* __restrict__ out_r, float* __restrict__ out_i)
{
    __shared__ float xr_s[4][64], xi_s[4][64];

    const int t = threadIdx.x, ty = t >> 6, lane = t & 63;
    const int row = blockIdx.x * 4 + ty;
    const int base = row * 64;

    float a1r = h2f(o1r[base + lane]), a1i = h2f(o1i[base + lane]);
    float a2r = h2f(o2r[base + lane]), a2i = h2f(o2i[base + lane]);

    float ss = a1r * a1r + a1i * a1i + a2r * a2r + a2i * a2i;
    #pragma unroll
    for (int m = 1; m < 64; m <<= 1) ss += __shfl_xor(ss, m);
    float inv = 1.f / sqrtf(ss * (1.f / 128.f) + 1e-5f);

    int src = lane >> 1;
    float e1r = __shfl(a1r, src), e1i = __shfl(a1i, src);
    float e2r = __shfl(a2r, src), e2i = __shfl(a2i, src);
    float c_r = (lane & 1) ? e2r : e1r;
    float c_i = (lane & 1) ? e2i : e1i;

    float sw = subw[lane];
    float ar_ = c_r * inv * sw;
    float ai_ = c_i * inv * sw;

    float g_r = out_gr[base + lane], g_i = out_gi[base + lane];
    xr_s[ty][lane] = g_r * ar_ - g_i * ai_;
    xi_s[ty][lane] = g_r * ai_ + g_i * ar_;
    __syncthreads();

    float accr = 0.f, acci = 0.f;
    const float4* wr4 = (const float4*)(owr + lane * 64);
    const float4* wi4 = (const float4*)(owi + lane * 64);
    #pragma unroll 4
    for (int d4 = 0; d4 < 16; ++d4) {
        float4 a = wr4[d4];
        float4 b = wi4[d4];
        const float* av = (const float*)&a;
        const float* bv = (const float*)&b;
        #pragma unroll
        for (int j = 0; j < 4; ++j) {
            float xrv = xr_s[ty][d4 * 4 + j], xiv = xi_s[ty][d4 * 4 + j];
            accr += xrv * av[j] - xiv * bv[j];
            acci += xrv * bv[j] + xiv * av[j];
        }
    }
    out_r[base + lane] = accr + obr[lane];
    out_i[base + lane] = acci + obi[lane];
}

// ---------------------------------------------------------------------------
extern "C" void kernel_launch(void* const* d_in, const int* in_sizes, int n_in,
                              void* d_out, int out_size, void* d_ws, size_t ws_size,
                              hipStream_t stream)
{
    (void)in_sizes; (void)n_in; (void)out_size; (void)ws_size;

    float* out    = (float*)d_out;
    float* out_r  = out;
    float* out_i  = out + (size_t)NTOT;
    float* out_gr = out + 2 * (size_t)NTOT;
    float* out_gi = out + 3 * (size_t)NTOT;

    // workspace layout (f16 only), 24 MB total
    char* w = (char*)d_ws;
    const size_t N = (size_t)NTOT;
    u16* q1r = (u16*)w; w += N * 2;
    u16* q1i = (u16*)w; w += N * 2;
    u16* q2r = (u16*)w; w += N * 2;
    u16* q2i = (u16*)w; w += N * 2;
    u16* kpr = (u16*)w; w += N * 2;
    u16* kpi = (u16*)w; w += N * 2;
    u16* vtr = (u16*)w; w += N * 2;   // [h][d][s]
    u16* vti = (u16*)w; w += N * 2;   // [h][d][s]
    u16* o1r = (u16*)w; w += N * 2;
    u16* o1i = (u16*)w; w += N * 2;
    u16* o2r = (u16*)w; w += N * 2;
    u16* o2i = (u16*)w; w += N * 2;

    proj_kernel<<<dim3(1024), dim3(256), 0, stream>>>(
        (const float*)d_in[0], (const float*)d_in[1],
        (const float*)d_in[2], (const float*)d_in[3],
        (const float*)d_in[4], (const float*)d_in[5],
        (const float*)d_in[6], (const float*)d_in[7],
        (const float*)d_in[8], (const float*)d_in[9],
        (const float*)d_in[10], (const float*)d_in[11],
        (const float*)d_in[12], (const float*)d_in[13],
        (const float*)d_in[14], (const float*)d_in[15],
        (const float*)d_in[16], (const float*)d_in[17],
        (const float*)d_in[18], (const float*)d_in[19],
        (const float*)d_in[20], (const float*)d_in[21],
        (const float*)d_in[22], (const float*)d_in[23],
        (const float*)d_in[24], (const float*)d_in[25],
        q1r, q1i, q2r, q2i, kpr, kpi, vtr, vti, out_gr, out_gi);

    attn_kernel<<<dim3(SQ / 64, 2, NH), dim3(256), 0, stream>>>(
        q1r, q1i, q2r, q2i, kpr, kpi, vtr, vti, o1r, o1i, o2r, o2i);

    epi_kernel<<<dim3(NH * SQ / 4), dim3(256), 0, stream>>>(
        o1r, o1i, o2r, o2i, out_gr, out_gi,
        (const float*)d_in[34], (const float*)d_in[26], (const float*)d_in[27],
        (const float*)d_in[28], (const float*)d_in[29],
        out_r, out_i);
}

// Round 9
// 303.391 us; speedup vs baseline: 1.2218x; 1.1887x over previous
//
#include <hip/hip_runtime.h>
#include <hip/hip_bf16.h>

#define NH 8
#define SQ 2048
#define HD 64
#define NTOT (NH * SQ * HD)   // 1048576
#define PIT 72                 // LDS row pitch in u16

typedef unsigned short u16;
typedef unsigned int u32;
typedef __attribute__((ext_vector_type(8))) unsigned short us8;
typedef __attribute__((ext_vector_type(4))) unsigned short us4v;
typedef __attribute__((ext_vector_type(8))) _Float16 h8;   // MFMA f16 A/B fragment
typedef __attribute__((ext_vector_type(4))) float f4;      // MFMA C/D fragment
typedef __attribute__((ext_vector_type(4))) u32 u4;

#define MFMA_F16 __builtin_amdgcn_mfma_f32_16x16x32_f16

__device__ __forceinline__ u16 f2h(float f) {
    union { _Float16 h; u16 u; } c; c.h = (_Float16)f; return c.u;
}
__device__ __forceinline__ float h2f(u16 u) {
    union { _Float16 h; u16 u; } c; c.u = u; return (float)c.h;
}
__device__ __forceinline__ h8 neg_h8(h8 a) {
    union { h8 h; u4 u; } c; c.h = a;
    c.u ^= 0x80008000u;
    return c.h;
}
// 8 contiguous f32 -> f16x8 fragment (two float4 loads, hw cvt)
__device__ __forceinline__ h8 pack8h(const float* p) {
    float4 a = ((const float4*)p)[0];
    float4 b = ((const float4*)p)[1];
    h8 r;
    r[0] = (_Float16)a.x; r[1] = (_Float16)a.y; r[2] = (_Float16)a.z; r[3] = (_Float16)a.w;
    r[4] = (_Float16)b.x; r[5] = (_Float16)b.y; r[6] = (_Float16)b.z; r[7] = (_Float16)b.w;
    return r;
}

struct Afrag { h8 r0, r1, i0, i1, ni0, ni1; };

// ---------------------------------------------------------------------------
// Kernel 1: MFMA complex projections (unchanged from round 8).
// ---------------------------------------------------------------------------
__global__ __launch_bounds__(256) void proj_kernel(
    const float* __restrict__ q_r, const float* __restrict__ q_i,
    const float* __restrict__ k_r, const float* __restrict__ k_i,
    const float* __restrict__ v_r, const float* __restrict__ v_i,
    const float* __restrict__ pe_q_r, const float* __restrict__ pe_q_i,
    const float* __restrict__ pe_k_r, const float* __restrict__ pe_k_i,
    const float* __restrict__ qwr, const float* __restrict__ qwi,
    const float* __restrict__ qbr, const float* __restrict__ qbi,
    const float* __restrict__ kwr, const float* __restrict__ kwi,
    const float* __restrict__ kbr, const float* __restrict__ kbi,
    const float* __restrict__ vwr, const float* __restrict__ vwi,
    const float* __restrict__ vbr, const float* __restrict__ vbi,
    const float* __restrict__ gwr, const float* __restrict__ gwi,
    const float* __restrict__ gbr, const float* __restrict__ gbi,
    u16* __restrict__ q1r, u16* __restrict__ q1i,
    u16* __restrict__ q2r, u16* __restrict__ q2i,
    u16* __restrict__ kpr, u16* __restrict__ kpi,
    u16* __restrict__ vtr, u16* __restrict__ vti,
    float* __restrict__ out_gr, float* __restrict__ out_gi)
{
    const int t = threadIdx.x;
    const int wv = t >> 6, l = t & 63;
    const int quad = l >> 4, m16 = l & 15;
    const int rowbase = blockIdx.x * 16;
    const int arow = rowbase + m16;
    const int h = rowbase >> 11;
    const int c0 = quad * 8;

    auto loadA = [&](const float* pr, const float* pi) {
        Afrag a;
        const float* rp = pr + arow * 64;
        const float* ip = pi + arow * 64;
        a.r0 = pack8h(rp + c0);      a.r1 = pack8h(rp + 32 + c0);
        a.i0 = pack8h(ip + c0);      a.i1 = pack8h(ip + 32 + c0);
        a.ni0 = neg_h8(a.i0);        a.ni1 = neg_h8(a.i1);
        return a;
    };

    auto ctile = [&](const Afrag& A, const float* wr, const float* wi, int cb,
                     f4& Cr, f4& Ci) {
        const float* wrp = wr + (cb + m16) * 64;
        const float* wip = wi + (cb + m16) * 64;
        h8 Br0 = pack8h(wrp + c0), Br1 = pack8h(wrp + 32 + c0);
        h8 Bi0 = pack8h(wip + c0), Bi1 = pack8h(wip + 32 + c0);
        Cr = (f4)0.f; Ci = (f4)0.f;
        Cr = MFMA_F16(A.r0,  Br0, Cr, 0, 0, 0);
        Cr = MFMA_F16(A.r1,  Br1, Cr, 0, 0, 0);
        Cr = MFMA_F16(A.ni0, Bi0, Cr, 0, 0, 0);
        Cr = MFMA_F16(A.ni1, Bi1, Cr, 0, 0, 0);
        Ci = MFMA_F16(A.r0,  Bi0, Ci, 0, 0, 0);
        Ci = MFMA_F16(A.r1,  Bi1, Ci, 0, 0, 0);
        Ci = MFMA_F16(A.i0,  Br0, Ci, 0, 0, 0);
        Ci = MFMA_F16(A.i1,  Br1, Ci, 0, 0, 0);
    };

    auto qtile = [&](const Afrag& A, int nt) {
        f4 Cr, Ci;
        ctile(A, qwr, qwi, nt * 16, Cr, Ci);
        int c = nt * 16 + m16;
        float br = qbr[c], bi = qbi[c];
        int dd = c >> 1, pc = c & 63;
        u16* dR = (c & 1) ? q2r : q1r;
        u16* dI = (c & 1) ? q2i : q1i;
        #pragma unroll
        for (int r = 0; r < 4; ++r) {
            int g = rowbase + quad * 4 + r;
            dR[g * 64 + dd] = f2h(Cr[r] + br + pe_q_r[g * 64 + pc]);
            dI[g * 64 + dd] = f2h(Ci[r] + bi + pe_q_i[g * 64 + pc]);
        }
    };
    auto ktile = [&](const Afrag& A, int nt) {
        f4 Cr, Ci;
        ctile(A, kwr, kwi, nt * 16, Cr, Ci);
        int c = nt * 16 + m16;
        float br = kbr[c], bi = kbi[c];
        #pragma unroll
        for (int r = 0; r < 4; ++r) {
            int g = rowbase + quad * 4 + r;
            kpr[g * 64 + c] = f2h(Cr[r] + br + pe_k_r[g * 64 + c]);
            kpi[g * 64 + c] = f2h(Ci[r] + bi + pe_k_i[g * 64 + c]);
        }
    };
    auto vtile = [&](const Afrag& A, int nt) {
        f4 Cr, Ci;
        ctile(A, vwr, vwi, nt * 16, Cr, Ci);
        int c = nt * 16 + m16;
        float br = vbr[c], bi = vbi[c];
        int s0 = (rowbase & 2047) + quad * 4;
        size_t tix = (size_t)(h * 64 + c) * 2048 + s0;
        us4v pr, pi;
        #pragma unroll
        for (int r = 0; r < 4; ++r) {
            pr[r] = f2h(Cr[r] + br);
            pi[r] = f2h(Ci[r] + bi);
        }
        *(us4v*)&vtr[tix] = pr;
        *(us4v*)&vti[tix] = pi;
    };
    auto gtile = [&](const Afrag& A, int nt) {
        f4 Cr, Ci;
        ctile(A, gwr, gwi, nt * 16, Cr, Ci);
        int c = nt * 16 + m16;
        float br = gbr[c], bi = gbi[c];
        #pragma unroll
        for (int r = 0; r < 4; ++r) {
            int g = rowbase + quad * 4 + r;
            out_gr[g * 64 + c] = Cr[r] + br;
            out_gi[g * 64 + c] = Ci[r] + bi;
        }
    };

    if (wv == 0) {
        Afrag Aq = loadA(q_r, q_i);
        qtile(Aq, 0); qtile(Aq, 1); qtile(Aq, 2); qtile(Aq, 3); qtile(Aq, 4);
    } else if (wv == 1) {
        Afrag Aq = loadA(q_r, q_i);
        qtile(Aq, 5); qtile(Aq, 6); qtile(Aq, 7);
        gtile(Aq, 0); gtile(Aq, 1);
    } else if (wv == 2) {
        Afrag Ak = loadA(k_r, k_i);
        ktile(Ak, 0); ktile(Ak, 1); ktile(Ak, 2); ktile(Ak, 3);
        Afrag Aq = loadA(q_r, q_i);
        gtile(Aq, 2);
    } else {
        Afrag Av = loadA(v_r, v_i);
        vtile(Av, 0); vtile(Av, 1); vtile(Av, 2); vtile(Av, 3);
        Afrag Aq = loadA(q_r, q_i);
        gtile(Aq, 3);
    }
}

// ---------------------------------------------------------------------------
// Kernel 2: MFMA flash attention (unchanged from round 8).
// ---------------------------------------------------------------------------
__global__ __launch_bounds__(256) void attn_kernel(
    const u16* __restrict__ q1r, const u16* __restrict__ q1i,
    const u16* __restrict__ q2r, const u16* __restrict__ q2i,
    const u16* __restrict__ kpr, const u16* __restrict__ kpi,
    const u16* __restrict__ vtr, const u16* __restrict__ vti,
    u16* __restrict__ o1r, u16* __restrict__ o1i,
    u16* __restrict__ o2r, u16* __restrict__ o2i)
{
    __shared__ __align__(16) u16 Kr[64][PIT], Ki[64][PIT];
    __shared__ __align__(16) u16 Vr[64][PIT], Vi[64][PIT];
    __shared__ __align__(16) u16 Pb[64][PIT];

    const int t  = threadIdx.x;
    const int qt = blockIdx.x;
    const int br = blockIdx.y;
    const int h  = blockIdx.z;

    const int wq   = t >> 6;
    const int l    = t & 63;
    const int quad = l >> 4;
    const int m    = l & 15;

    const u16* Qsr = br ? q2r : q1r;
    const u16* Qsi = br ? q2i : q1i;
    const int hbase = h * SQ * 64;
    const int qbase = hbase + qt * 64 * 64;
    const int vbase = h * 64 * SQ;

    const u16* qrr = Qsr + qbase + (wq * 16 + m) * 64;
    const u16* qri = Qsi + qbase + (wq * 16 + m) * 64;
    h8 Qr0 = *(const h8*)(qrr + quad * 8);
    h8 Qr1 = *(const h8*)(qrr + 32 + quad * 8);
    h8 Qi0 = *(const h8*)(qri + quad * 8);
    h8 Qi1 = *(const h8*)(qri + 32 + quad * 8);
    h8 nQr0 = neg_h8(Qr0);
    h8 nQr1 = neg_h8(Qr1);

    h8 ones;
    #pragma unroll
    for (int j = 0; j < 8; ++j) ones[j] = (_Float16)1.0f;

    float mreg[4];
    #pragma unroll
    for (int r = 0; r < 4; ++r) mreg[r] = -1e30f;
    f4 Ovr[4], Ovi[4], Lacc = (f4)0.f;
    #pragma unroll
    for (int d = 0; d < 4; ++d) { Ovr[d] = (f4)0.f; Ovi[d] = (f4)0.f; }

    for (int kt = 0; kt < 32; ++kt) {
        __syncthreads();
        {
            const int kb = hbase + kt * 64 * 64;
            const int vb = vbase + kt * 64;
            for (int i = t; i < 512; i += 256) {
                int r = i >> 3, c8 = (i & 7) * 8;
                *(us8*)&Kr[r][c8] = *(const us8*)(kpr + kb + r * 64 + c8);
                *(us8*)&Ki[r][c8] = *(const us8*)(kpi + kb + r * 64 + c8);
                *(us8*)&Vr[r][c8] = *(const us8*)(vtr + vb + r * SQ + c8);
                *(us8*)&Vi[r][c8] = *(const us8*)(vti + vb + r * SQ + c8);
            }
        }
        __syncthreads();

        float sv[4][4];
        #pragma unroll
        for (int nt = 0; nt < 4; ++nt) {
            const int kr = nt * 16 + m;
            h8 k0 = *(const h8*)&Kr[kr][quad * 8];
            h8 k1 = *(const h8*)&Kr[kr][32 + quad * 8];
            h8 c0 = *(const h8*)&Ki[kr][quad * 8];
            h8 c1 = *(const h8*)&Ki[kr][32 + quad * 8];
            f4 ar = (f4)0.f, ai = (f4)0.f;
            ar = MFMA_F16(Qr0, k0, ar, 0, 0, 0);
            ar = MFMA_F16(Qr1, k1, ar, 0, 0, 0);
            ar = MFMA_F16(Qi0, c0, ar, 0, 0, 0);
            ar = MFMA_F16(Qi1, c1, ar, 0, 0, 0);
            ai = MFMA_F16(Qi0, k0, ai, 0, 0, 0);
            ai = MFMA_F16(Qi1, k1, ai, 0, 0, 0);
            ai = MFMA_F16(nQr0, c0, ai, 0, 0, 0);
            ai = MFMA_F16(nQr1, c1, ai, 0, 0, 0);
            #pragma unroll
            for (int r = 0; r < 4; ++r)
                sv[nt][r] = sqrtf(ar[r] * ar[r] + ai[r] * ai[r] + 1e-8f) * 0.125f;
        }

        float al[4];
        #pragma unroll
        for (int r = 0; r < 4; ++r) {
            float rv = fmaxf(fmaxf(sv[0][r], sv[1][r]), fmaxf(sv[2][r], sv[3][r]));
            rv = fmaxf(rv, __shfl_xor(rv, 1));
            rv = fmaxf(rv, __shfl_xor(rv, 2));
            rv = fmaxf(rv, __shfl_xor(rv, 4));
            rv = fmaxf(rv, __shfl_xor(rv, 8));
            float mn = fmaxf(mreg[r], rv);
            al[r] = __expf(mreg[r] - mn);
            mreg[r] = mn;
            #pragma unroll
            for (int nt = 0; nt < 4; ++nt)
                Pb[wq * 16 + quad * 4 + r][nt * 16 + m] = f2h(__expf(sv[nt][r] - mn));
        }

        h8 pa0 = *(const h8*)&Pb[wq * 16 + m][quad * 8];
        h8 pa1 = *(const h8*)&Pb[wq * 16 + m][32 + quad * 8];

        #pragma unroll
        for (int r = 0; r < 4; ++r) Lacc[r] *= al[r];
        Lacc = MFMA_F16(pa0, ones, Lacc, 0, 0, 0);
        Lacc = MFMA_F16(pa1, ones, Lacc, 0, 0, 0);

        #pragma unroll
        for (int dt = 0; dt < 4; ++dt) {
            #pragma unroll
            for (int r = 0; r < 4; ++r) { Ovr[dt][r] *= al[r]; Ovi[dt][r] *= al[r]; }
            const int vr_ = dt * 16 + m;
            h8 b0 = *(const h8*)&Vr[vr_][quad * 8];
            h8 b1 = *(const h8*)&Vr[vr_][32 + quad * 8];
            h8 d0 = *(const h8*)&Vi[vr_][quad * 8];
            h8 d1 = *(const h8*)&Vi[vr_][32 + quad * 8];
            Ovr[dt] = MFMA_F16(pa0, b0, Ovr[dt], 0, 0, 0);
            Ovr[dt] = MFMA_F16(pa1, b1, Ovr[dt], 0, 0, 0);
            Ovi[dt] = MFMA_F16(pa0, d0, Ovi[dt], 0, 0, 0);
            Ovi[dt] = MFMA_F16(pa1, d1, Ovi[dt], 0, 0, 0);
        }
    }

    {
        u16* Dr = br ? o2r : o1r;
        u16* Di = br ? o2i : o1i;
        float inv[4];
        #pragma unroll
        for (int r = 0; r < 4; ++r) inv[r] = 1.f / Lacc[r];
        #pragma unroll
        for (int dt = 0; dt < 4; ++dt) {
            #pragma unroll
            for (int r = 0; r < 4; ++r) {
                int q = wq * 16 + quad * 4 + r;
                Dr[qbase + q * 64 + dt * 16 + m] = f2h(Ovr[dt][r] * inv[r]);
                Di[qbase + q * 64 + dt * 16 + m] = f2h(Ovi[dt][r] * inv[r]);
            }
        }
    }
}

// ---------------------------------------------------------------------------
// Kernel 3: MFMA epilogue.  Grid 1024 x 256; block = 16 rows.
// Stage o1/o2 coalesced -> LDS; per-thread RMS partials + 16-lane shfl;
// interleave + subw + gate -> x (f16, LDS, pitch 72); each wave does one
// 16-col complex n-tile of the out-projection with coalesced-per-row
// weight reads (proj-style), bias, coalesced f32 stores.
// ---------------------------------------------------------------------------
__global__ __launch_bounds__(256) void epi_kernel(
    const u16* __restrict__ o1r, const u16* __restrict__ o1i,
    const u16* __restrict__ o2r, const u16* __restrict__ o2i,
    const float* __restrict__ out_gr, const float* __restrict__ out_gi,
    const float* __restrict__ subw,
    const float* __restrict__ owr, const float* __restrict__ owi,
    const float* __restrict__ obr, const float* __restrict__ obi,
    float* __restrict__ out_r, float* __restrict__ out_i)
{
    __shared__ __align__(16) u16 L1r[16][64], L1i[16][64];
    __shared__ __align__(16) u16 L2r[16][64], L2i[16][64];
    __shared__ __align__(16) u16 Xr[16][PIT], Xi[16][PIT];

    const int t = threadIdx.x;
    const int rowbase = blockIdx.x * 16;

    // ---- stage o1/o2 (coalesced 8B loads) ----
    {
        int r = t >> 4, c4 = (t & 15) * 4;
        size_t gi = (size_t)(rowbase + r) * 64 + c4;
        *(us4v*)&L1r[r][c4] = *(const us4v*)(o1r + gi);
        *(us4v*)&L1i[r][c4] = *(const us4v*)(o1i + gi);
        *(us4v*)&L2r[r][c4] = *(const us4v*)(o2r + gi);
        *(us4v*)&L2i[r][c4] = *(const us4v*)(o2i + gi);
    }
    __syncthreads();

    // ---- RMS (joint over o1,o2 = all 128 interleaved cols) + x ----
    {
        int r = t >> 4, c4 = (t & 15) * 4;
        float ss = 0.f;
        #pragma unroll
        for (int j = 0; j < 4; ++j) {
            float a = h2f(L1r[r][c4 + j]), b = h2f(L1i[r][c4 + j]);
            float c = h2f(L2r[r][c4 + j]), d = h2f(L2i[r][c4 + j]);
            ss += a * a + b * b + c * c + d * d;
        }
        ss += __shfl_xor(ss, 1);
        ss += __shfl_xor(ss, 2);
        ss += __shfl_xor(ss, 4);
        ss += __shfl_xor(ss, 8);
        float inv = 1.f / sqrtf(ss * (1.f / 128.f) + 1e-5f);

        float4 g_r = *(const float4*)(out_gr + (size_t)(rowbase + r) * 64 + c4);
        float4 g_i = *(const float4*)(out_gi + (size_t)(rowbase + r) * 64 + c4);
        const float* grv = (const float*)&g_r;
        const float* giv = (const float*)&g_i;

        us4v xrp, xip;
        #pragma unroll
        for (int j = 0; j < 4; ++j) {
            int c = c4 + j;
            int s = c >> 1;
            float cr_ = (c & 1) ? h2f(L2r[r][s]) : h2f(L1r[r][s]);
            float ci_ = (c & 1) ? h2f(L2i[r][s]) : h2f(L1i[r][s]);
            float sw = subw[c];
            float ar_ = cr_ * inv * sw;
            float ai_ = ci_ * inv * sw;
            xrp[j] = f2h(grv[j] * ar_ - giv[j] * ai_);
            xip[j] = f2h(grv[j] * ai_ + giv[j] * ar_);
        }
        *(us4v*)&Xr[r][c4] = xrp;
        *(us4v*)&Xi[r][c4] = xip;
    }
    __syncthreads();

    // ---- out-projection: wave w = n-tile w ----
    const int wv = t >> 6, l = t & 63;
    const int quad = l >> 4, m16 = l & 15;
    const int c0 = quad * 8;

    h8 Ar0 = *(const h8*)&Xr[m16][c0];
    h8 Ar1 = *(const h8*)&Xr[m16][32 + c0];
    h8 Ai0 = *(const h8*)&Xi[m16][c0];
    h8 Ai1 = *(const h8*)&Xi[m16][32 + c0];
    h8 nAi0 = neg_h8(Ai0), nAi1 = neg_h8(Ai1);

    const int c = wv * 16 + m16;
    const float* wrp = owr + c * 64;
    const float* wip = owi + c * 64;
    h8 Br0 = pack8h(wrp + c0), Br1 = pack8h(wrp + 32 + c0);
    h8 Bi0 = pack8h(wip + c0), Bi1 = pack8h(wip + 32 + c0);

    f4 Cr = (f4)0.f, Ci = (f4)0.f;
    Cr = MFMA_F16(Ar0,  Br0, Cr, 0, 0, 0);
    Cr = MFMA_F16(Ar1,  Br1, Cr, 0, 0, 0);
    Cr = MFMA_F16(nAi0, Bi0, Cr, 0, 0, 0);
    Cr = MFMA_F16(nAi1, Bi1, Cr, 0, 0, 0);
    Ci = MFMA_F16(Ar0,  Bi0, Ci, 0, 0, 0);
    Ci = MFMA_F16(Ar1,  Bi1, Ci, 0, 0, 0);
    Ci = MFMA_F16(Ai0,  Br0, Ci, 0, 0, 0);
    Ci = MFMA_F16(Ai1,  Br1, Ci, 0, 0, 0);

    float br_ = obr[c], bi_ = obi[c];
    #pragma unroll
    for (int r = 0; r < 4; ++r) {
        size_t g = (size_t)(rowbase + quad * 4 + r) * 64 + c;
        out_r[g] = Cr[r] + br_;
        out_i[g] = Ci[r] + bi_;
    }
}

// ---------------------------------------------------------------------------
extern "C" void kernel_launch(void* const* d_in, const int* in_sizes, int n_in,
                              void* d_out, int out_size, void* d_ws, size_t ws_size,
                              hipStream_t stream)
{
    (void)in_sizes; (void)n_in; (void)out_size; (void)ws_size;

    float* out    = (float*)d_out;
    float* out_r  = out;
    float* out_i  = out + (size_t)NTOT;
    float* out_gr = out + 2 * (size_t)NTOT;
    float* out_gi = out + 3 * (size_t)NTOT;

    // workspace layout (f16 only), 24 MB total
    char* w = (char*)d_ws;
    const size_t N = (size_t)NTOT;
    u16* q1r = (u16*)w; w += N * 2;
    u16* q1i = (u16*)w; w += N * 2;
    u16* q2r = (u16*)w; w += N * 2;
    u16* q2i = (u16*)w; w += N * 2;
    u16* kpr = (u16*)w; w += N * 2;
    u16* kpi = (u16*)w; w += N * 2;
    u16* vtr = (u16*)w; w += N * 2;   // [h][d][s]
    u16* vti = (u16*)w; w += N * 2;   // [h][d][s]
    u16* o1r = (u16*)w; w += N * 2;
    u16* o1i = (u16*)w; w += N * 2;
    u16* o2r = (u16*)w; w += N * 2;
    u16* o2i = (u16*)w; w += N * 2;

    proj_kernel<<<dim3(1024), dim3(256), 0, stream>>>(
        (const float*)d_in[0], (const float*)d_in[1],
        (const float*)d_in[2], (const float*)d_in[3],
        (const float*)d_in[4], (const float*)d_in[5],
        (const float*)d_in[6], (const float*)d_in[7],
        (const float*)d_in[8], (const float*)d_in[9],
        (const float*)d_in[10], (const float*)d_in[11],
        (const float*)d_in[12], (const float*)d_in[13],
        (const float*)d_in[14], (const float*)d_in[15],
        (const float*)d_in[16], (const float*)d_in[17],
        (const float*)d_in[18], (const float*)d_in[19],
        (const float*)d_in[20], (const float*)d_in[21],
        (const float*)d_in[22], (const float*)d_in[23],
        (const float*)d_in[24], (const float*)d_in[25],
        q1r, q1i, q2r, q2i, kpr, kpi, vtr, vti, out_gr, out_gi);

    attn_kernel<<<dim3(SQ / 64, 2, NH), dim3(256), 0, stream>>>(
        q1r, q1i, q2r, q2i, kpr, kpi, vtr, vti, o1r, o1i, o2r, o2i);

    epi_kernel<<<dim3(1024), dim3(256), 0, stream>>>(
        o1r, o1i, o2r, o2i, out_gr, out_gi,
        (const float*)d_in[34], (const float*)d_in[26], (const float*)d_in[27],
        (const float*)d_in[28], (const float*)d_in[29],
        out_r, out_i);
}